// Round 11
// baseline (148.612 us; speedup 1.0000x reference)
//
#include <hip/hip_runtime.h>
#include <hip/hip_bf16.h>

// ---------------------------------------------------------------------------
// PlainSelfAttention (2quad, tau-scaled) on MI355X.
//  x[2,2048,1024] fp32, Wqkv[1024,3072], Wo[1024,1024], tau[16]
// R11: (a) attn: explicit 2-stage kb pipeline — QK^T for BOTH 32-k blocks
//      first (s[2][2]), then pack/PV per block, so PV(0) MFMAs overlap
//      pack(1) VALU and QK(1) covers pack(0). (b) gemm_out retiled 128x64
//      -> 512 blocks (was 256 = 1 block/CU, 1 wave/SIMD). (c) XCD-aware
//      block swizzle on both GEMMs (768%8==0, 512%8==0).
// ---------------------------------------------------------------------------

typedef unsigned short ushort_t;
typedef __attribute__((ext_vector_type(8))) short short8;
typedef __attribute__((ext_vector_type(4))) float f32x4;
typedef __attribute__((ext_vector_type(16))) float f32x16;

#define B_      2
#define T_      2048
#define C_      1024
#define HEADS_  16
#define D_      64

union frag_u { unsigned u[4]; short8 s8; };

__device__ __forceinline__ ushort_t f2bf(float f) {
  __hip_bfloat16 h = __float2bfloat16(f);           // RNE
  return *reinterpret_cast<ushort_t*>(&h);
}

__device__ __forceinline__ unsigned cvt_pk_bf16(float lo, float hi) {
  unsigned r;
  asm("v_cvt_pk_bf16_f32 %0, %1, %2" : "=v"(r) : "v"(lo), "v"(hi));
  return r;
}

__device__ __forceinline__ void permlane32_swap(unsigned &a, unsigned &b) {
  asm volatile("v_permlane32_swap_b32 %0, %1" : "+v"(a), "+v"(b));
}

__device__ __forceinline__ f32x16 zero16() {
  f32x16 z;
#pragma unroll
  for (int i = 0; i < 16; ++i) z[i] = 0.f;
  return z;
}

// -------------------------- cast x (fp32 -> bf16) --------------------------
__global__ __launch_bounds__(256) void cast_x_kernel(const float* __restrict__ x,
                                                     ushort_t* __restrict__ xb) {
  int i = blockIdx.x * 256 + threadIdx.x;
  float4 f = ((const float4*)x)[i];
  ushort_t* o = xb + (size_t)i * 4;
  o[0] = f2bf(f.x); o[1] = f2bf(f.y); o[2] = f2bf(f.z); o[3] = f2bf(f.w);
}

// ------------------ transpose + cast weights (fp32->bf16) ------------------
__global__ __launch_bounds__(256) void transpose_cast_w(const float* __restrict__ in,
                                                        ushort_t* __restrict__ out,
                                                        int R, int Cc) {
  __shared__ float tile[64][65];
  int rb = blockIdx.y, cb = blockIdx.x;
  int c = threadIdx.x & 63;
  int r0 = threadIdx.x >> 6;
#pragma unroll
  for (int i = 0; i < 16; ++i) {
    int r = r0 + i * 4;
    tile[r][c] = in[(size_t)(rb * 64 + r) * Cc + cb * 64 + c];
  }
  __syncthreads();
#pragma unroll
  for (int i = 0; i < 16; ++i) {
    int r = r0 + i * 4;
    out[(size_t)(cb * 64 + r) * R + rb * 64 + c] = f2bf(tile[c][r]);
  }
}

// ------------------------- transpose v -> vT (bf16) ------------------------
__global__ __launch_bounds__(256) void transpose_v_kernel(const ushort_t* __restrict__ v,
                                                          ushort_t* __restrict__ vT) {
  __shared__ ushort_t tile[64][72];
  int bh = blockIdx.y, tb = blockIdx.x;
  int c = threadIdx.x & 63;
  int r0 = threadIdx.x >> 6;
#pragma unroll
  for (int i = 0; i < 16; ++i) {
    int r = r0 + i * 4;
    tile[r][c] = v[((size_t)bh * T_ + tb * 64 + r) * D_ + c];
  }
  __syncthreads();
#pragma unroll
  for (int i = 0; i < 16; ++i) {
    int r = r0 + i * 4;
    vT[((size_t)bh * D_ + r) * T_ + tb * 64 + c] = tile[c][r];
  }
}

// -------------------- shared GEMM mainloop (bf16 MFMA) ---------------------
__device__ __forceinline__ void gemm_tile(const ushort_t* __restrict__ A,
                                          const ushort_t* __restrict__ Bt,
                                          int K, int tm, int tn,
                                          ushort_t* lds, f32x4 acc[4][4]) {
  const int tid = threadIdx.x;
  const int lane = tid & 63, wave = tid >> 6;
  const int wm = wave >> 1, wn = wave & 1;
  const int lr = lane & 15, lk = lane >> 4;
  ushort_t* As = lds;               // [128][72]
  ushort_t* Bs = lds + 128 * 72;    // [128][72]
  const ushort_t* Ag = A + (size_t)tm * 128 * K;
  const ushort_t* Bg = Bt + (size_t)tn * 128 * K;

  for (int kt = 0; kt < K; kt += 64) {
#pragma unroll
    for (int i = 0; i < 4; ++i) {
      int cch = tid + i * 256; int row = cch >> 3, kc = cch & 7;
      *(short8*)&As[row * 72 + kc * 8] =
          *(const short8*)&Ag[(size_t)row * K + kt + kc * 8];
    }
#pragma unroll
    for (int i = 0; i < 4; ++i) {
      int cch = tid + i * 256; int row = cch >> 3, kc = cch & 7;
      *(short8*)&Bs[row * 72 + kc * 8] =
          *(const short8*)&Bg[(size_t)row * K + kt + kc * 8];
    }
    __syncthreads();
#pragma unroll
    for (int kk = 0; kk < 64; kk += 32) {
      short8 a[4], b[4];
#pragma unroll
      for (int m = 0; m < 4; ++m)
        a[m] = *(const short8*)&As[(wm * 64 + m * 16 + lr) * 72 + kk + lk * 8];
#pragma unroll
      for (int n = 0; n < 4; ++n)
        b[n] = *(const short8*)&Bs[(wn * 64 + n * 16 + lr) * 72 + kk + lk * 8];
#pragma unroll
      for (int m = 0; m < 4; ++m)
#pragma unroll
        for (int n = 0; n < 4; ++n)
          acc[m][n] = __builtin_amdgcn_mfma_f32_16x16x32_bf16(a[m], b[n], acc[m][n], 0, 0, 0);
    }
    __syncthreads();
  }
}

// -------------------- GEMM1: qkv = xb @ Wqkv^T, scatter --------------------
// grid 768 blocks, XCD-swizzled: 96 consecutive linear ids per XCD.
__global__ __launch_bounds__(256) void gemm_qkv(const ushort_t* __restrict__ xb,
                                                const ushort_t* __restrict__ wT,
                                                ushort_t* __restrict__ qg,
                                                ushort_t* __restrict__ kg,
                                                ushort_t* __restrict__ vg) {
  __shared__ __align__(16) ushort_t lds[2 * 128 * 72];
  int id = blockIdx.y * 24 + blockIdx.x;       // 0..767, x fastest
  int sw = (id & 7) * 96 + (id >> 3);          // bijective (768 % 8 == 0)
  int tm = sw / 24, tn = sw % 24;

  f32x4 acc[4][4];
#pragma unroll
  for (int m = 0; m < 4; ++m)
#pragma unroll
    for (int n = 0; n < 4; ++n) acc[m][n] = (f32x4){0.f, 0.f, 0.f, 0.f};

  gemm_tile(xb, wT, C_, tm, tn, lds, acc);

  const int lane = threadIdx.x & 63, wave = threadIdx.x >> 6;
  const int wm = wave >> 1, wn = wave & 1;
  const int lr = lane & 15, lk = lane >> 4;
#pragma unroll
  for (int m = 0; m < 4; ++m)
#pragma unroll
    for (int n = 0; n < 4; ++n)
#pragma unroll
      for (int r = 0; r < 4; ++r) {
        int row = tm * 128 + wm * 64 + m * 16 + lk * 4 + r;  // = b*T + t
        int col = tn * 128 + wn * 64 + n * 16 + lr;          // [0,3072)
        int b = row >> 11, t = row & 2047;
        int part = col >> 10, idx = col & 1023;
        int h = idx >> 6, j = idx & 63;
        ushort_t* dst = (part == 0) ? qg : (part == 1) ? kg : vg;
        dst[(((size_t)(b * HEADS_ + h)) * T_ + t) * D_ + j] = f2bf(acc[m][n][r]);
      }
}

// ---------------------- GEMM2: out = attn_bf16 @ Wo^T ----------------------
// 128x64 tile, grid (16 N, 32 M) = 512 blocks (2/CU; was 256 = 1/CU,
// 1 wave/SIMD with every stall exposed). 4 waves stacked on M (32 rows each).
__global__ __launch_bounds__(256) void gemm_out(const ushort_t* __restrict__ ab,
                                                const ushort_t* __restrict__ woT,
                                                float* __restrict__ out) {
  __shared__ __align__(16) ushort_t As[128 * 72];
  __shared__ __align__(16) ushort_t Bs[64 * 72];
  const int tid = threadIdx.x;
  const int lane = tid & 63, wave = tid >> 6;
  const int lr = lane & 15, lk = lane >> 4;

  int id = blockIdx.y * 16 + blockIdx.x;       // 0..511
  int sw = (id & 7) * 64 + (id >> 3);          // bijective (512 % 8 == 0)
  int tm = sw / 16, tn = sw % 16;

  const ushort_t* Ag = ab  + (size_t)tm * 128 * C_;
  const ushort_t* Bg = woT + (size_t)tn * 64 * C_;

  f32x4 acc[2][4];
#pragma unroll
  for (int m = 0; m < 2; ++m)
#pragma unroll
    for (int n = 0; n < 4; ++n) acc[m][n] = (f32x4){0.f, 0.f, 0.f, 0.f};

  for (int kt = 0; kt < C_; kt += 64) {
#pragma unroll
    for (int i = 0; i < 4; ++i) {
      int cch = tid + i * 256; int row = cch >> 3, kc = cch & 7;
      *(short8*)&As[row * 72 + kc * 8] =
          *(const short8*)&Ag[(size_t)row * C_ + kt + kc * 8];
    }
#pragma unroll
    for (int i = 0; i < 2; ++i) {
      int cch = tid + i * 256; int row = cch >> 3, kc = cch & 7;
      *(short8*)&Bs[row * 72 + kc * 8] =
          *(const short8*)&Bg[(size_t)row * C_ + kt + kc * 8];
    }
    __syncthreads();
#pragma unroll
    for (int kk = 0; kk < 64; kk += 32) {
      short8 a[2], b[4];
#pragma unroll
      for (int m = 0; m < 2; ++m)
        a[m] = *(const short8*)&As[(wave * 32 + m * 16 + lr) * 72 + kk + lk * 8];
#pragma unroll
      for (int n = 0; n < 4; ++n)
        b[n] = *(const short8*)&Bs[(n * 16 + lr) * 72 + kk + lk * 8];
#pragma unroll
      for (int m = 0; m < 2; ++m)
#pragma unroll
        for (int n = 0; n < 4; ++n)
          acc[m][n] = __builtin_amdgcn_mfma_f32_16x16x32_bf16(a[m], b[n], acc[m][n], 0, 0, 0);
    }
    __syncthreads();
  }

#pragma unroll
  for (int m = 0; m < 2; ++m)
#pragma unroll
    for (int n = 0; n < 4; ++n)
#pragma unroll
      for (int r = 0; r < 4; ++r) {
        int row = tm * 128 + wave * 32 + m * 16 + lk * 4 + r;
        int col = tn * 64 + n * 16 + lr;
        out[(size_t)row * C_ + col] = acc[m][n][r];
      }
}

// --------------------------- fused 2quad attention -------------------------
// Block = (bh, 128 q-rows), 4 waves = 2 q-groups (wq) x 2 KV-splits (wk),
// KV tile = 128k, double-buffered LDS (one barrier/round), T14 reg prefetch.
// R11: 2-stage kb pipeline — QK^T for BOTH kb blocks first, then per-kb
// pack+PV, creating MFMA work (PV0/QK1) that overlaps the pack VALU chains.
__global__ __launch_bounds__(256, 2) void attn_kernel(const ushort_t* __restrict__ qg,
                                                      const ushort_t* __restrict__ kg,
                                                      const ushort_t* __restrict__ vTg,
                                                      const float* __restrict__ tau,
                                                      ushort_t* __restrict__ attn_out) {
  // per buffer: Ks [128][72] (9216) | Vts [64][136] (8704) = 17920 ushorts
  __shared__ __align__(16) ushort_t kvbuf[2][17920];             // 71.7 KB
  __shared__ float denom_lds[2][2][2][32];                       // [wk][wq][qb][q]

  const int tid = threadIdx.x, lane = tid & 63;
  const int w = tid >> 6, wq = w >> 1, wk = w & 1;
  const int l31 = lane & 31, hi = lane >> 5, hi8 = hi * 8;
  const int qt = blockIdx.x, bh = blockIdx.y;
  const int b = bh >> 4, h = bh & 15;
  const float inv = 1.0f / (8.0f * tau[h]);   // sqrt(64)*tau

  const ushort_t* kb_ = kg  + (size_t)bh * T_ * D_;
  const ushort_t* vb_ = vTg + (size_t)bh * D_ * T_;
  const ushort_t* qp  = qg  + ((size_t)bh * T_ + qt * 128 + wq * 64) * D_;

  // per-thread staging coordinates (constant across tiles)
  const int krow[4] = { (tid) >> 3, (tid + 256) >> 3, (tid + 512) >> 3, (tid + 768) >> 3 };
  const int kcol = (tid & 7) * 8;
  const int vrow[4] = { (tid) >> 4, (tid + 256) >> 4, (tid + 512) >> 4, (tid + 768) >> 4 };
  const int vcol = (tid & 15) * 8;

  // Q B-frags in registers, loop-invariant.
  short8 qf[2][4];
#pragma unroll
  for (int qb = 0; qb < 2; ++qb)
#pragma unroll
    for (int dc = 0; dc < 4; ++dc)
      qf[qb][dc] = *(const short8*)&qp[(qb * 32 + l31) * D_ + dc * 16 + hi8];

  f32x16 acc[2][2];   // [qb][db]: D[q=crow(r,hi)][d=db*32+l31]
  acc[0][0] = zero16(); acc[0][1] = zero16();
  acc[1][0] = zero16(); acc[1][1] = zero16();
  float denomp[2] = {0.f, 0.f};

  // ---- prologue: load tile 0 into registers ----
  short8 kreg[4], vreg[4];
#pragma unroll
  for (int i = 0; i < 4; ++i) {
    kreg[i] = *(const short8*)&kb_[(size_t)krow[i] * D_ + kcol];
    vreg[i] = *(const short8*)&vb_[(size_t)vrow[i] * T_ + vcol];
  }

  const int NT = T_ / 128;
  for (int rnd = 0; rnd < NT; ++rnd) {
    ushort_t* Ks  = kvbuf[rnd & 1];
    ushort_t* Vts = kvbuf[rnd & 1] + 9216;

    // publish tile rnd from regs to this round's buffer
#pragma unroll
    for (int i = 0; i < 4; ++i) {
      *(short8*)&Ks[krow[i] * 72 + kcol] = kreg[i];
      *(short8*)&Vts[vrow[i] * 136 + vcol] = vreg[i];
    }
    __syncthreads();                           // the ONLY barrier per round

    // prefetch tile rnd+1 (consumed at next publish -> waitcnt after compute)
    if (rnd + 1 < NT) {
      const int kv0 = (rnd + 1) * 128;
#pragma unroll
      for (int i = 0; i < 4; ++i) {
        kreg[i] = *(const short8*)&kb_[(size_t)(kv0 + krow[i]) * D_ + kcol];
        vreg[i] = *(const short8*)&vb_[(size_t)vrow[i] * T_ + kv0 + vcol];
      }
    }

    // ---- stage 1: QK^T for BOTH 32-k blocks (s[kb][qb]) ----
    f32x16 s[2][2];
    s[0][0] = zero16(); s[0][1] = zero16();
    s[1][0] = zero16(); s[1][1] = zero16();
    __builtin_amdgcn_s_setprio(1);
#pragma unroll
    for (int kb = 0; kb < 2; ++kb) {
      const int krow0 = wk * 64 + kb * 32;
#pragma unroll
      for (int dc = 0; dc < 4; ++dc) {
        short8 kf = *(const short8*)&Ks[(krow0 + l31) * 72 + dc * 16 + hi8];
        s[kb][0] = __builtin_amdgcn_mfma_f32_32x32x16_bf16(kf, qf[0][dc], s[kb][0], 0, 0, 0);
        s[kb][1] = __builtin_amdgcn_mfma_f32_32x32x16_bf16(kf, qf[1][dc], s[kb][1], 0, 0, 0);
      }
    }
    __builtin_amdgcn_s_setprio(0);

    // ---- stage 2: per-kb pack + PV (PV(0) MFMAs overlap pack(1) VALU) ----
#pragma unroll
    for (int kb = 0; kb < 2; ++kb) {
      const int krow0 = wk * 64 + kb * 32;
      frag_u ef[2][2];
#pragma unroll
      for (int qb = 0; qb < 2; ++qb) {
        float ev[16];
        float dsum = 0.f;
#pragma unroll
        for (int r = 0; r < 16; ++r) {
          float t = fmaf(s[kb][qb][r], inv, 5.0f);
          ev[r] = t * t;
          dsum += ev[r];
        }
        denomp[qb] += dsum;
        unsigned P[8];
#pragma unroll
        for (int p = 0; p < 8; ++p) P[p] = cvt_pk_bf16(ev[2 * p], ev[2 * p + 1]);
        unsigned a0 = P[0], b0 = P[2]; permlane32_swap(a0, b0);
        unsigned a1 = P[1], b1 = P[3]; permlane32_swap(a1, b1);
        ef[qb][0].u[0] = a0; ef[qb][0].u[1] = a1; ef[qb][0].u[2] = b0; ef[qb][0].u[3] = b1;
        unsigned a2 = P[4], b2 = P[6]; permlane32_swap(a2, b2);
        unsigned a3 = P[5], b3 = P[7]; permlane32_swap(a3, b3);
        ef[qb][1].u[0] = a2; ef[qb][1].u[1] = a3; ef[qb][1].u[2] = b2; ef[qb][1].u[3] = b3;
      }

      __builtin_amdgcn_s_setprio(1);
#pragma unroll
      for (int c = 0; c < 2; ++c)
#pragma unroll
        for (int db = 0; db < 2; ++db) {
          short8 vf = *(const short8*)&Vts[(db * 32 + l31) * 136 + krow0 + c * 16 + hi8];
          acc[0][db] = __builtin_amdgcn_mfma_f32_32x32x16_bf16(ef[0][c].s8, vf, acc[0][db], 0, 0, 0);
          acc[1][db] = __builtin_amdgcn_mfma_f32_32x32x16_bf16(ef[1][c].s8, vf, acc[1][db], 0, 0, 0);
        }
      __builtin_amdgcn_s_setprio(0);
    }
    // no trailing barrier: next publish writes the other buffer
  }

  // ---------------- epilogue: combine KV halves, normalize ----------------
#pragma unroll
  for (int qb = 0; qb < 2; ++qb) {
    float v = denomp[qb];
    v += __shfl_xor(v, 32);                    // combine hi halves
    if (lane < 32) denom_lds[wk][wq][qb][l31] = v;
  }
  // out_lds reuses buf0 (last compute read buf1 since NT-1=15 is odd)
  float* out_lds = (float*)kvbuf[0];           // [2 wq][64 q][64 d] fp32 (32 KB)
  if (wk == 1) {
#pragma unroll
    for (int qb = 0; qb < 2; ++qb)
#pragma unroll
      for (int db = 0; db < 2; ++db)
#pragma unroll
        for (int r = 0; r < 16; ++r) {
          int qr = qb * 32 + (r & 3) + 8 * (r >> 2) + 4 * hi;
          out_lds[(wq * 64 + qr) * 64 + db * 32 + l31] = acc[qb][db][r];
        }
  }
  __syncthreads();
  if (wk == 0) {
#pragma unroll
    for (int qb = 0; qb < 2; ++qb)
#pragma unroll
      for (int r = 0; r < 16; ++r) {
        int cr = (r & 3) + 8 * (r >> 2) + 4 * hi;
        int qr = qb * 32 + cr;
        float dt = denom_lds[0][wq][qb][cr] + denom_lds[1][wq][qb][cr];
        float dinv = 1.0f / (dt + 1e-6f);
#pragma unroll
        for (int db = 0; db < 2; ++db) {
          float val = acc[qb][db][r] + out_lds[(wq * 64 + qr) * 64 + db * 32 + l31];
          int grow = b * T_ + qt * 128 + wq * 64 + qr;
          attn_out[(size_t)grow * C_ + h * 64 + db * 32 + l31] = f2bf(val * dinv);
        }
      }
  }
}

// ---------------------------------------------------------------------------
extern "C" void kernel_launch(void* const* d_in, const int* in_sizes, int n_in,
                              void* d_out, int out_size, void* d_ws, size_t ws_size,
                              hipStream_t stream) {
  const float* x    = (const float*)d_in[0];
  const float* Wqkv = (const float*)d_in[1];
  const float* Wo   = (const float*)d_in[2];
  const float* tau  = (const float*)d_in[3];
  float* out = (float*)d_out;

  char* ws = (char*)d_ws;
  ushort_t* xb    = (ushort_t*)(ws);                 //  8,388,608 B
  ushort_t* wqkvT = (ushort_t*)(ws + 8388608);       //  6,291,456 B
  ushort_t* woT   = (ushort_t*)(ws + 14680064);      //  2,097,152 B
  ushort_t* qg    = (ushort_t*)(ws + 16777216);      //  8,388,608 B
  ushort_t* kg    = (ushort_t*)(ws + 25165824);      //  8,388,608 B
  ushort_t* ab    = (ushort_t*)(ws + 33554432);      //  8,388,608 B  (total ~42 MB)
  // v and vT scratch live in d_out (16,777,216 B) — consumed before gemm_out
  // overwrites d_out with the final fp32 result.
  ushort_t* vg  = (ushort_t*)d_out;
  ushort_t* vTg = (ushort_t*)d_out + 4194304;

  cast_x_kernel<<<4096, 256, 0, stream>>>(x, xb);
  transpose_cast_w<<<dim3(48, 16), 256, 0, stream>>>(Wqkv, wqkvT, 1024, 3072);
  transpose_cast_w<<<dim3(16, 16), 256, 0, stream>>>(Wo, woT, 1024, 1024);
  gemm_qkv<<<dim3(24, 32), 256, 0, stream>>>(xb, wqkvT, qg, kg, vg);
  transpose_v_kernel<<<dim3(32, 32), 256, 0, stream>>>(vg, vTg);
  attn_kernel<<<dim3(16, 32), 256, 0, stream>>>(qg, kg, vTg, tau, ab);
  gemm_out<<<dim3(16, 32), 256, 0, stream>>>(ab, woT, out);
}